// Round 6
// baseline (124.469 us; speedup 1.0000x reference)
//
#include <hip/hip_runtime.h>
#include <math.h>

#define B_ 16
#define T_ 2048
#define N_ 8
#define D_ 512
#define TTILE 32

// DIAGNOSTIC ROUND: fft launched with 32x grid, main with 2x grid. Replica
// blocks compute bit-identical values and store to the SAME addresses
// (benign duplicate writes -> deterministic, validation-safe). This pushes
// both kernels above the ~40us harness fills so rocprof top-5 shows their
// per-dispatch counters (VGPR_Count, VALUBusy, WRITE_SIZE, LDS conflicts).

// -2*pi/2048
#define NEG_W0 (-3.0679615757712823e-3f)
// -2*pi/32
#define NEG_W32 (-0.19634954084936207f)
// -2*pi/1024
#define NEG_W1024 (-6.1359231515425647e-3f)
// -2*ln(10000)/512
#define NEG_LDIV (-0.035977892078031555f)

__global__ __launch_bounds__(512) void fft_kernel(
    const float* __restrict__ x, float* __restrict__ pmax,
    float* __restrict__ nyqS) {
  __shared__ __align__(16) float2 ybuf[1024];
  __shared__ __align__(16) float2 Bl[1024];
  __shared__ float swav[8];
  __shared__ float pwav[8];
  int tid = threadIdx.x;
  int inner = blockIdx.x & 255;          // 32 replicas do identical work
  int bn = inner >> 1, parity = inner & 1;
  int b = bn >> 3, n = bn & 7;
  const float* xb = x + (size_t)b * (T_ * N_) + n;

  float v0 = xb[tid * 8];
  float v1 = xb[(tid + 512) * 8];
  float v2 = xb[(tid + 1024) * 8];
  float v3 = xb[(tid + 1536) * 8];
  float ea = v0 + v2, eb = v1 + v3;
  float sgn = (tid & 1) ? -(ea + eb) : (ea + eb);
#pragma unroll
  for (int off = 32; off > 0; off >>= 1) sgn += __shfl_down(sgn, off);
  if ((tid & 63) == 0) swav[tid >> 6] = sgn;

  if (parity == 0) {
    float* ya = (float*)ybuf;
    ya[tid] = ea;
    ya[tid + 512] = eb;
  } else {
    float oa = v0 - v2, ob = v1 - v3;
    float ca, sa, cb, sb;
    sincosf((float)tid * NEG_W0, &sa, &ca);
    sincosf((float)(tid + 512) * NEG_W0, &sb, &cb);
    ybuf[tid] = make_float2(oa * ca, oa * sa);
    ybuf[tid + 512] = make_float2(ob * cb, ob * sb);
  }
  __syncthreads();

  int m0 = tid & 31, t0a = tid >> 5;
  float d1 = (float)m0 * NEG_W32;
  float K1 = 2.0f * cosf(d1);
  float c = 1.f, s = 0.f, cp, sp;
  sincosf(-d1, &sp, &cp);
  float ar0 = 0.f, ai0 = 0.f, ar1 = 0.f, ai1 = 0.f;
  if (parity == 0) {
    const float* ya = (const float*)ybuf;
#pragma unroll 8
    for (int t1 = 0; t1 < 32; ++t1) {
      float y0 = ya[t1 * 32 + t0a];
      float y1 = ya[t1 * 32 + t0a + 16];
      ar0 = fmaf(y0, c, ar0); ai0 = fmaf(y0, s, ai0);
      ar1 = fmaf(y1, c, ar1); ai1 = fmaf(y1, s, ai1);
      float nc = fmaf(K1, c, -cp), ns = fmaf(K1, s, -sp);
      cp = c; sp = s; c = nc; s = ns;
    }
  } else {
#pragma unroll 8
    for (int t1 = 0; t1 < 32; ++t1) {
      float2 y0 = ybuf[t1 * 32 + t0a];
      float2 y1 = ybuf[t1 * 32 + t0a + 16];
      ar0 = fmaf(y0.x, c, fmaf(-y0.y, s, ar0));
      ai0 = fmaf(y0.x, s, fmaf(y0.y, c, ai0));
      ar1 = fmaf(y1.x, c, fmaf(-y1.y, s, ar1));
      ai1 = fmaf(y1.x, s, fmaf(y1.y, c, ai1));
      float nc = fmaf(K1, c, -cp), ns = fmaf(K1, s, -sp);
      cp = c; sp = s; c = nc; s = ns;
    }
  }
  {
    float ct, st;
    sincosf((float)(t0a * m0) * NEG_W1024, &st, &ct);
    Bl[t0a * 32 + m0] =
        make_float2(ar0 * ct - ai0 * st, fmaf(ar0, st, ai0 * ct));
    sincosf((float)((t0a + 16) * m0) * NEG_W1024, &st, &ct);
    Bl[(t0a + 16) * 32 + m0] =
        make_float2(ar1 * ct - ai1 * st, fmaf(ar1, st, ai1 * ct));
  }
  __syncthreads();

  int m02 = tid & 31, m1 = tid >> 5;
  float d2 = (float)m1 * NEG_W32;
  float K2 = 2.0f * cosf(d2);
  float c2 = 1.f, s2 = 0.f, c2p, s2p;
  sincosf(-d2, &s2p, &c2p);
  float yr = 0.f, yi = 0.f;
#pragma unroll 8
  for (int t0 = 0; t0 < 32; ++t0) {
    float2 bv = Bl[t0 * 32 + m02];
    yr = fmaf(bv.x, c2, fmaf(-bv.y, s2, yr));
    yi = fmaf(bv.x, s2, fmaf(bv.y, c2, yi));
    float nc = fmaf(K2, c2, -c2p), ns = fmaf(K2, s2, -s2p);
    c2p = c2; s2p = s2; c2 = nc; s2 = ns;
  }
  float P = fmaf(yr, yr, yi * yi);
#pragma unroll
  for (int off = 32; off > 0; off >>= 1) P = fmaxf(P, __shfl_down(P, off));
  if ((tid & 63) == 0) pwav[tid >> 6] = P;
  __syncthreads();
  if (tid < 8) {
    float mx = pwav[tid];
    float sv = swav[tid];
#pragma unroll
    for (int off = 4; off > 0; off >>= 1) {
      mx = fmaxf(mx, __shfl_down(mx, off));
      sv += __shfl_down(sv, off);
    }
    if (tid == 0) {
      pmax[inner] = mx;                  // identical value from all replicas
      if (parity == 0) nyqS[bn] = sv;
    }
  }
}

// Fused: circular conv1d (k=3) + temporal (register mark-counts) + cycle pos.
__global__ __launch_bounds__(256) void main_kernel(
    const float* __restrict__ x, const int* __restrict__ xmark,
    const float* __restrict__ convw, const float* __restrict__ pmax,
    const float* __restrict__ nyqS, float* __restrict__ out) {
  __shared__ __align__(16) float xs[TTILE + 2][8];
  __shared__ __align__(16) float cnt[TTILE][8];
  __shared__ int xm[TTILE][4];
  int tid = threadIdx.x;
  int inner = blockIdx.x & 1023;         // 2 replicas do identical work
  int b = inner >> 6;                    // 64 t-tiles per batch (TTILE=32)
  int t0 = (inner & 63) * TTILE;

  {
    int r = tid >> 3, n = tid & 7;
    int tg = (t0 - 1 + r) & (T_ - 1);
    xs[r][n] = x[(b * T_ + tg) * N_ + n];
    if (tid < 16) {
      int r2 = 32 + (tid >> 3), n2 = tid & 7;
      int tg2 = (t0 - 1 + r2) & (T_ - 1);
      xs[r2][n2] = x[(b * T_ + tg2) * N_ + n2];
    }
    if (tid < TTILE * 4) {
      ((int*)xm)[tid] = xmark[(b * T_ + t0) * 4 + tid];
    }
  }
  __syncthreads();
  {
    int tt = tid >> 3, p = tid & 7;
    int c = 0;
#pragma unroll
    for (int q = 0; q < 4; ++q) c += (xm[tt][q] == p) ? 1 : 0;
    cnt[tt][p] = (float)c;
  }

  float W[48];
  const float4* wp = (const float4*)(convw + tid * 48);
#pragma unroll
  for (int q = 0; q < 12; ++q) {
    float4 v = wp[q];
    W[4 * q + 0] = v.x; W[4 * q + 1] = v.y; W[4 * q + 2] = v.z; W[4 * q + 3] = v.w;
  }
  float divv = expf((float)tid * NEG_LDIV);
  float s1, c1;
  sincosf(divv, &s1, &c1);
  float sr[7], cr[7];
  sr[0] = 0.f; cr[0] = 1.f; sr[1] = s1; cr[1] = c1;
#pragma unroll
  for (int p = 2; p < 7; ++p) {
    sr[p] = fmaf(sr[p - 1], c1, cr[p - 1] * s1);
    cr[p] = fmaf(cr[p - 1], c1, -sr[p - 1] * s1);
  }
  int m = 0;
#pragma unroll
  for (int nn = 0; nn < 8; ++nn) {
    int bn = b * 8 + nn;
    float mx = fmaxf(pmax[2 * bn], pmax[2 * bn + 1]);
    float S = nyqS[bn];
    if (S * S > mx) ++m;
  }
  float w1 = (float)(8 - m) * 0.125f;
  float w0 = (float)m * 0.125f;
  float sv, cv;
  sincosf((float)t0 * divv, &sv, &cv);
  __syncthreads();

  float win[3][8];
#pragma unroll
  for (int r = 0; r < 2; ++r) {
    float4 a = *(const float4*)&xs[r][0];
    float4 bq = *(const float4*)&xs[r][4];
    win[r][0] = a.x; win[r][1] = a.y; win[r][2] = a.z; win[r][3] = a.w;
    win[r][4] = bq.x; win[r][5] = bq.y; win[r][6] = bq.z; win[r][7] = bq.w;
  }
#pragma unroll
  for (int tt = 0; tt < TTILE; ++tt) {
    int wl = (tt + 2) % 3;
    {
      float4 a = *(const float4*)&xs[tt + 2][0];
      float4 bq = *(const float4*)&xs[tt + 2][4];
      win[wl][0] = a.x; win[wl][1] = a.y; win[wl][2] = a.z; win[wl][3] = a.w;
      win[wl][4] = bq.x; win[wl][5] = bq.y; win[wl][6] = bq.z; win[wl][7] = bq.w;
    }
    const float* x0 = win[tt % 3];
    const float* x1 = win[(tt + 1) % 3];
    const float* x2 = win[wl];
    float a0 = 0.f, a1 = 0.f;
#pragma unroll
    for (int n = 0; n < 8; ++n) {
      a0 = fmaf(x0[n], W[n * 3 + 0], a0);
      a0 = fmaf(x1[n], W[n * 3 + 1], a0);
      a0 = fmaf(x2[n], W[n * 3 + 2], a0);
      a1 = fmaf(x0[n], W[24 + n * 3 + 0], a1);
      a1 = fmaf(x1[n], W[24 + n * 3 + 1], a1);
      a1 = fmaf(x2[n], W[24 + n * 3 + 2], a1);
    }
    float4 ca = *(const float4*)&cnt[tt][0];
    float4 cb = *(const float4*)&cnt[tt][4];
    float e0 = ca.y * sr[1];
    e0 = fmaf(ca.z, sr[2], e0); e0 = fmaf(ca.w, sr[3], e0);
    e0 = fmaf(cb.x, sr[4], e0); e0 = fmaf(cb.y, sr[5], e0);
    e0 = fmaf(cb.z, sr[6], e0);
    float e1 = ca.x;
    e1 = fmaf(ca.y, cr[1], e1); e1 = fmaf(ca.z, cr[2], e1);
    e1 = fmaf(ca.w, cr[3], e1); e1 = fmaf(cb.x, cr[4], e1);
    e1 = fmaf(cb.y, cr[5], e1); e1 = fmaf(cb.z, cr[6], e1);
    float o0 = a0 + e0 + w1 * sv;
    float o1 = a1 + e1 + fmaf(w1, cv, w0);
    *(float2*)(out + (size_t)((b * T_ + t0 + tt) * D_ + 2 * tid)) =
        make_float2(o0, o1);
    float ns = fmaf(sv, c1, cv * s1);
    float nc = fmaf(cv, c1, -sv * s1);
    sv = ns; cv = nc;
  }
}

extern "C" void kernel_launch(void* const* d_in, const int* in_sizes, int n_in,
                              void* d_out, int out_size, void* d_ws, size_t ws_size,
                              hipStream_t stream) {
  const float* x = (const float*)d_in[0];
  const int* xmark = (const int*)d_in[1];
  const float* convw = (const float*)d_in[2];
  float* out = (float*)d_out;

  float* pmax = (float*)d_ws;        // 256 floats
  float* nyqS = pmax + 256;          // 128 floats

  // DIAGNOSTIC: 32x fft replicas, 2x main replicas (identical work+stores)
  fft_kernel<<<256 * 32, 512, 0, stream>>>(x, pmax, nyqS);
  main_kernel<<<1024 * 2, 256, 0, stream>>>(x, xmark, convw, pmax, nyqS, out);
}

// Round 7
// 85.372 us; speedup vs baseline: 1.4580x; 1.4580x over previous
//
#include <hip/hip_runtime.h>
#include <math.h>

#define B_ 16
#define T_ 2048
#define N_ 8
#define D_ 512
#define TTILE 32
#define OUT_ELEMS (B_ * T_ * D_)   // 16,777,216 floats = 64 MiB

// -2*pi/2048
#define NEG_W0 (-3.0679615757712823e-3f)
// -2*pi/32
#define NEG_W32 (-0.19634954084936207f)
// -2*pi/1024
#define NEG_W1024 (-6.1359231515425647e-3f)
// -2*ln(10000)/512
#define NEG_LDIV (-0.035977892078031555f)

// ws layout: [0,1MiB) pmax[256]+nyqS[128] (+slack); [1MiB, 1MiB+3*64MiB)
// optional replica store regions for the diagnostic main replicas.

// One block per (bn, parity), 1024 threads (16 waves -> good latency hiding).
// Radix-32 two-stage Cooley-Tukey of the folded 1024-point DFT:
//   stage 1: thread (t0=tid>>5, m0=tid&31): A = sum_{t1<32} y[32t1+t0] W32^{t1 m0}
//   fine twiddle W1024^{t0 m0} -> B
//   stage 2: thread (h=tid>>9, m1=(tid>>5)&15, m02=tid&31):
//            partial over t0 in [16h,16h+16) of B[t0][m02] W32^{t0 m1}
// Nyquist X_1024 = sum_{t<1024} (-1)^t e_t (parity-0 block stores it).
__global__ __launch_bounds__(1024) void fft_kernel(
    const float* __restrict__ x, float* __restrict__ pmax,
    float* __restrict__ nyqS) {
  __shared__ __align__(16) float2 ybuf[1024];  // parity0 uses first half as float[1024]
  __shared__ __align__(16) float2 Bl[1024];
  __shared__ __align__(16) float2 part[1024];
  __shared__ float swav[16];
  __shared__ float pwav[8];
  int tid = threadIdx.x;
  int blk = blockIdx.x;
  int bn = blk >> 1, parity = blk & 1;
  int b = bn >> 3, n = bn & 7;
  const float* xb = x + (size_t)b * (T_ * N_) + n;

  float va = xb[tid * 8];
  float vb = xb[(tid + 1024) * 8];
  float ea = va + vb;                     // e[tid]
  float sgn = (tid & 1) ? -ea : ea;       // Nyquist partial (-1)^t e_t
#pragma unroll
  for (int off = 32; off > 0; off >>= 1) sgn += __shfl_down(sgn, off);
  if ((tid & 63) == 0) swav[tid >> 6] = sgn;

  if (parity == 0) {
    ((float*)ybuf)[tid] = ea;
  } else {
    float o = va - vb;
    float c0, s0;
    sincosf((float)tid * NEG_W0, &s0, &c0);
    ybuf[tid] = make_float2(o * c0, o * s0);
  }
  __syncthreads();

  // ---- stage 1 ----
  int m0 = tid & 31, t0 = tid >> 5;
  float d1 = (float)m0 * NEG_W32;
  float K1 = 2.0f * cosf(d1);
  float c = 1.f, s = 0.f, cp, sp;
  sincosf(-d1, &sp, &cp);                 // angle at t1 = -1
  float ar = 0.f, ai = 0.f;
  if (parity == 0) {
    const float* ya = (const float*)ybuf;
#pragma unroll 8
    for (int t1 = 0; t1 < 32; ++t1) {
      float y = ya[t1 * 32 + t0];         // half-wave broadcast
      ar = fmaf(y, c, ar); ai = fmaf(y, s, ai);
      float nc = fmaf(K1, c, -cp), ns = fmaf(K1, s, -sp);
      cp = c; sp = s; c = nc; s = ns;
    }
  } else {
#pragma unroll 8
    for (int t1 = 0; t1 < 32; ++t1) {
      float2 y = ybuf[t1 * 32 + t0];
      ar = fmaf(y.x, c, fmaf(-y.y, s, ar));
      ai = fmaf(y.x, s, fmaf(y.y, c, ai));
      float nc = fmaf(K1, c, -cp), ns = fmaf(K1, s, -sp);
      cp = c; sp = s; c = nc; s = ns;
    }
  }
  {
    float ct, st;
    sincosf((float)(t0 * m0) * NEG_W1024, &st, &ct);
    Bl[t0 * 32 + m0] = make_float2(ar * ct - ai * st, fmaf(ar, st, ai * ct));
  }
  __syncthreads();

  // ---- stage 2 (split t0-range across block halves) ----
  int m02 = tid & 31;
  int m1 = (tid >> 5) & 15;
  int h = tid >> 9;
  float d2 = (float)m1 * NEG_W32;
  float K2 = 2.0f * cosf(d2);
  int t0s = h * 16;
  float c2, s2, c2p, s2p;
  sincosf((float)t0s * d2, &s2, &c2);
  sincosf((float)(t0s - 1) * d2, &s2p, &c2p);
  float yr = 0.f, yi = 0.f;
#pragma unroll 8
  for (int j = 0; j < 16; ++j) {
    float2 bv = Bl[(t0s + j) * 32 + m02];
    yr = fmaf(bv.x, c2, fmaf(-bv.y, s2, yr));
    yi = fmaf(bv.x, s2, fmaf(bv.y, c2, yi));
    float nc = fmaf(K2, c2, -c2p), ns = fmaf(K2, s2, -s2p);
    c2p = c2; s2p = s2; c2 = nc; s2 = ns;
  }
  part[tid] = make_float2(yr, yi);
  __syncthreads();
  if (tid < 512) {
    float2 pa = part[tid], pb = part[tid + 512];
    float rr = pa.x + pb.x, ii = pa.y + pb.y;
    float P = fmaf(rr, rr, ii * ii);
#pragma unroll
    for (int off = 32; off > 0; off >>= 1) P = fmaxf(P, __shfl_down(P, off));
    if ((tid & 63) == 0) pwav[tid >> 6] = P;
  }
  __syncthreads();
  if (tid < 64) {
    float mxv = (tid < 8) ? pwav[tid] : 0.f;
    float svv = (tid < 16) ? swav[tid] : 0.f;
#pragma unroll
    for (int off = 8; off > 0; off >>= 1) {
      mxv = fmaxf(mxv, __shfl_down(mxv, off));
      svv += __shfl_down(svv, off);
    }
    if (tid == 0) {
      pmax[blk] = mxv;                    // unconditional plain store
      if (parity == 0) nyqS[bn] = svv;
    }
  }
}

// Fused: circular conv1d (k=3) + temporal (register mark-counts) + cycle pos.
// DIAGNOSTIC: 4 replicas; replica 0 writes d_out, replicas 1-3 write disjoint
// ws regions (if ws is large enough; else duplicate-identical stores to out).
__global__ __launch_bounds__(256) void main_kernel(
    const float* __restrict__ x, const int* __restrict__ xmark,
    const float* __restrict__ convw, const float* __restrict__ pmax,
    const float* __restrict__ nyqS, float* out, float* alt, int use_alt) {
  __shared__ __align__(16) float xs[TTILE + 2][8];
  __shared__ __align__(16) float cnt[TTILE][8];
  __shared__ int xm[TTILE][4];
  int tid = threadIdx.x;
  int rep = blockIdx.x >> 10;
  int inner = blockIdx.x & 1023;
  int b = inner >> 6;                    // 64 t-tiles per batch (TTILE=32)
  int t0 = (inner & 63) * TTILE;
  float* obase = (rep > 0 && use_alt) ? (alt + (size_t)(rep - 1) * OUT_ELEMS)
                                      : out;

  {
    int r = tid >> 3, n = tid & 7;
    int tg = (t0 - 1 + r) & (T_ - 1);
    xs[r][n] = x[(b * T_ + tg) * N_ + n];
    if (tid < 16) {
      int r2 = 32 + (tid >> 3), n2 = tid & 7;
      int tg2 = (t0 - 1 + r2) & (T_ - 1);
      xs[r2][n2] = x[(b * T_ + tg2) * N_ + n2];
    }
    if (tid < TTILE * 4) {
      ((int*)xm)[tid] = xmark[(b * T_ + t0) * 4 + tid];
    }
  }
  __syncthreads();
  {
    int tt = tid >> 3, p = tid & 7;
    int c = 0;
#pragma unroll
    for (int q = 0; q < 4; ++q) c += (xm[tt][q] == p) ? 1 : 0;
    cnt[tt][p] = (float)c;
  }

  float W[48];
  const float4* wp = (const float4*)(convw + tid * 48);
#pragma unroll
  for (int q = 0; q < 12; ++q) {
    float4 v = wp[q];
    W[4 * q + 0] = v.x; W[4 * q + 1] = v.y; W[4 * q + 2] = v.z; W[4 * q + 3] = v.w;
  }
  float divv = expf((float)tid * NEG_LDIV);
  float s1, c1;
  sincosf(divv, &s1, &c1);
  float sr[7], cr[7];
  sr[0] = 0.f; cr[0] = 1.f; sr[1] = s1; cr[1] = c1;
#pragma unroll
  for (int p = 2; p < 7; ++p) {
    sr[p] = fmaf(sr[p - 1], c1, cr[p - 1] * s1);
    cr[p] = fmaf(cr[p - 1], c1, -sr[p - 1] * s1);
  }
  int m = 0;
#pragma unroll
  for (int nn = 0; nn < 8; ++nn) {
    int bn = b * 8 + nn;
    float mx = fmaxf(pmax[2 * bn], pmax[2 * bn + 1]);
    float S = nyqS[bn];
    if (S * S > mx) ++m;
  }
  float w1 = (float)(8 - m) * 0.125f;
  float w0 = (float)m * 0.125f;
  float sv, cv;
  sincosf((float)t0 * divv, &sv, &cv);
  __syncthreads();

  float win[3][8];
#pragma unroll
  for (int r = 0; r < 2; ++r) {
    float4 a = *(const float4*)&xs[r][0];
    float4 bq = *(const float4*)&xs[r][4];
    win[r][0] = a.x; win[r][1] = a.y; win[r][2] = a.z; win[r][3] = a.w;
    win[r][4] = bq.x; win[r][5] = bq.y; win[r][6] = bq.z; win[r][7] = bq.w;
  }
#pragma unroll
  for (int tt = 0; tt < TTILE; ++tt) {
    int wl = (tt + 2) % 3;
    {
      float4 a = *(const float4*)&xs[tt + 2][0];
      float4 bq = *(const float4*)&xs[tt + 2][4];
      win[wl][0] = a.x; win[wl][1] = a.y; win[wl][2] = a.z; win[wl][3] = a.w;
      win[wl][4] = bq.x; win[wl][5] = bq.y; win[wl][6] = bq.z; win[wl][7] = bq.w;
    }
    const float* x0 = win[tt % 3];
    const float* x1 = win[(tt + 1) % 3];
    const float* x2 = win[wl];
    float a0 = 0.f, a1 = 0.f;
#pragma unroll
    for (int n = 0; n < 8; ++n) {
      a0 = fmaf(x0[n], W[n * 3 + 0], a0);
      a0 = fmaf(x1[n], W[n * 3 + 1], a0);
      a0 = fmaf(x2[n], W[n * 3 + 2], a0);
      a1 = fmaf(x0[n], W[24 + n * 3 + 0], a1);
      a1 = fmaf(x1[n], W[24 + n * 3 + 1], a1);
      a1 = fmaf(x2[n], W[24 + n * 3 + 2], a1);
    }
    float4 ca = *(const float4*)&cnt[tt][0];
    float4 cb = *(const float4*)&cnt[tt][4];
    float e0 = ca.y * sr[1];
    e0 = fmaf(ca.z, sr[2], e0); e0 = fmaf(ca.w, sr[3], e0);
    e0 = fmaf(cb.x, sr[4], e0); e0 = fmaf(cb.y, sr[5], e0);
    e0 = fmaf(cb.z, sr[6], e0);
    float e1 = ca.x;
    e1 = fmaf(ca.y, cr[1], e1); e1 = fmaf(ca.z, cr[2], e1);
    e1 = fmaf(ca.w, cr[3], e1); e1 = fmaf(cb.x, cr[4], e1);
    e1 = fmaf(cb.y, cr[5], e1); e1 = fmaf(cb.z, cr[6], e1);
    float o0 = a0 + e0 + w1 * sv;
    float o1 = a1 + e1 + fmaf(w1, cv, w0);
    *(float2*)(obase + (size_t)((b * T_ + t0 + tt) * D_ + 2 * tid)) =
        make_float2(o0, o1);
    float ns = fmaf(sv, c1, cv * s1);
    float nc = fmaf(cv, c1, -sv * s1);
    sv = ns; cv = nc;
  }
}

extern "C" void kernel_launch(void* const* d_in, const int* in_sizes, int n_in,
                              void* d_out, int out_size, void* d_ws, size_t ws_size,
                              hipStream_t stream) {
  const float* x = (const float*)d_in[0];
  const int* xmark = (const int*)d_in[1];
  const float* convw = (const float*)d_in[2];
  float* out = (float*)d_out;

  float* pmax = (float*)d_ws;        // 256 floats
  float* nyqS = pmax + 256;          // 128 floats
  float* alt = (float*)((char*)d_ws + (1u << 20));
  size_t need = (1u << 20) + 3ull * (size_t)OUT_ELEMS * 4ull;
  int use_alt = (ws_size >= need) ? 1 : 0;   // constant per session -> deterministic

  fft_kernel<<<256, 1024, 0, stream>>>(x, pmax, nyqS);
  // DIAGNOSTIC: 4 main replicas (replica 0 -> real output)
  main_kernel<<<4096, 256, 0, stream>>>(x, xmark, convw, pmax, nyqS, out, alt,
                                        use_alt);
}

// Round 8
// 37.884 us; speedup vs baseline: 3.2855x; 2.2535x over previous
//
#include <hip/hip_runtime.h>
#include <math.h>

#define B_ 16
#define T_ 2048
#define N_ 8
#define D_ 512
#define NS 4            // t-subtiles (of 16) per block
#define DTW 4           // d-tiles (of 16) per wave

// -2*pi/2048
#define NEG_W0 (-3.0679615757712823e-3f)
// -2*pi/32
#define NEG_W32 (-0.19634954084936207f)
// -2*pi/1024
#define NEG_W1024 (-6.1359231515425647e-3f)
// -2*ln(10000)/512
#define NEG_LDIV (-0.035977892078031555f)

typedef __attribute__((ext_vector_type(8))) short bf16x8;
typedef __attribute__((ext_vector_type(4))) float f32x4;

// fp32 -> bf16 (round-to-nearest-even), self-contained
static __device__ __forceinline__ short f2bf(float f) {
  unsigned int u = __float_as_uint(f);
  unsigned int r = u + 0x7FFFu + ((u >> 16) & 1u);
  return (short)(r >> 16);
}

// ---------------- fft kernel (unchanged from R7; ~3-5us) ----------------
// One block per (bn, parity), 1024 threads. Radix-32 two-stage Cooley-Tukey
// of the folded 1024-point DFT; writes per-(bn,parity) spectrum max and the
// per-bn Nyquist sum, all via unconditional plain stores.
__global__ __launch_bounds__(1024) void fft_kernel(
    const float* __restrict__ x, float* __restrict__ pmax,
    float* __restrict__ nyqS) {
  __shared__ __align__(16) float2 ybuf[1024];
  __shared__ __align__(16) float2 Bl[1024];
  __shared__ __align__(16) float2 part[1024];
  __shared__ float swav[16];
  __shared__ float pwav[8];
  int tid = threadIdx.x;
  int blk = blockIdx.x;
  int bn = blk >> 1, parity = blk & 1;
  int b = bn >> 3, n = bn & 7;
  const float* xb = x + (size_t)b * (T_ * N_) + n;

  float va = xb[tid * 8];
  float vb = xb[(tid + 1024) * 8];
  float ea = va + vb;
  float sgn = (tid & 1) ? -ea : ea;
#pragma unroll
  for (int off = 32; off > 0; off >>= 1) sgn += __shfl_down(sgn, off);
  if ((tid & 63) == 0) swav[tid >> 6] = sgn;

  if (parity == 0) {
    ((float*)ybuf)[tid] = ea;
  } else {
    float o = va - vb;
    float c0, s0;
    sincosf((float)tid * NEG_W0, &s0, &c0);
    ybuf[tid] = make_float2(o * c0, o * s0);
  }
  __syncthreads();

  int m0 = tid & 31, t0 = tid >> 5;
  float d1 = (float)m0 * NEG_W32;
  float K1 = 2.0f * cosf(d1);
  float c = 1.f, s = 0.f, cp, sp;
  sincosf(-d1, &sp, &cp);
  float ar = 0.f, ai = 0.f;
  if (parity == 0) {
    const float* ya = (const float*)ybuf;
#pragma unroll 8
    for (int t1 = 0; t1 < 32; ++t1) {
      float y = ya[t1 * 32 + t0];
      ar = fmaf(y, c, ar); ai = fmaf(y, s, ai);
      float nc = fmaf(K1, c, -cp), ns = fmaf(K1, s, -sp);
      cp = c; sp = s; c = nc; s = ns;
    }
  } else {
#pragma unroll 8
    for (int t1 = 0; t1 < 32; ++t1) {
      float2 y = ybuf[t1 * 32 + t0];
      ar = fmaf(y.x, c, fmaf(-y.y, s, ar));
      ai = fmaf(y.x, s, fmaf(y.y, c, ai));
      float nc = fmaf(K1, c, -cp), ns = fmaf(K1, s, -sp);
      cp = c; sp = s; c = nc; s = ns;
    }
  }
  {
    float ct, st;
    sincosf((float)(t0 * m0) * NEG_W1024, &st, &ct);
    Bl[t0 * 32 + m0] = make_float2(ar * ct - ai * st, fmaf(ar, st, ai * ct));
  }
  __syncthreads();

  int m02 = tid & 31;
  int m1 = (tid >> 5) & 15;
  int h = tid >> 9;
  float d2 = (float)m1 * NEG_W32;
  float K2 = 2.0f * cosf(d2);
  int t0s = h * 16;
  float c2, s2, c2p, s2p;
  sincosf((float)t0s * d2, &s2, &c2);
  sincosf((float)(t0s - 1) * d2, &s2p, &c2p);
  float yr = 0.f, yi = 0.f;
#pragma unroll 8
  for (int j = 0; j < 16; ++j) {
    float2 bv = Bl[(t0s + j) * 32 + m02];
    yr = fmaf(bv.x, c2, fmaf(-bv.y, s2, yr));
    yi = fmaf(bv.x, s2, fmaf(bv.y, c2, yi));
    float nc = fmaf(K2, c2, -c2p), ns = fmaf(K2, s2, -s2p);
    c2p = c2; s2p = s2; c2 = nc; s2 = ns;
  }
  part[tid] = make_float2(yr, yi);
  __syncthreads();
  if (tid < 512) {
    float2 pa = part[tid], pb = part[tid + 512];
    float rr = pa.x + pb.x, ii = pa.y + pb.y;
    float P = fmaf(rr, rr, ii * ii);
#pragma unroll
    for (int off = 32; off > 0; off >>= 1) P = fmaxf(P, __shfl_down(P, off));
    if ((tid & 63) == 0) pwav[tid >> 6] = P;
  }
  __syncthreads();
  if (tid < 64) {
    float mxv = (tid < 8) ? pwav[tid] : 0.f;
    float svv = (tid < 16) ? swav[tid] : 0.f;
#pragma unroll
    for (int off = 8; off > 0; off >>= 1) {
      mxv = fmaxf(mxv, __shfl_down(mxv, off));
      svv += __shfl_down(svv, off);
    }
    if (tid == 0) {
      pmax[blk] = mxv;
      if (parity == 0) nyqS[bn] = svv;
    }
  }
}

// ---------------- main kernel: MFMA conv+temporal, VALU cyc ----------------
// One MFMA (16x16x32 bf16) per (d-tile, t-subtile) computes BOTH the circular
// conv1d (k-slots 0..23: kk=k*8+n -> A=W[d][n][k], B=x[t+k-1][n]) and the
// temporal embedding (k-slots 24..31: A=tab_p[d], B=cnt_p[t]) since
// E[t][d] = sum_p cnt_p[t]*tab_p[d]. Computed as C^T (A=weights, B=x) so each
// lane's f32x4 acc = 4 consecutive d at one t -> single float4 store.
// Correctness needs only slot-consistency of A/B (same bijection kk=g*8+j on
// both operands) + the HW-verified C layout (col=lane&15, row=(lane>>4)*4+r).
__global__ __launch_bounds__(512, 4) void main_kernel(
    const float* __restrict__ x, const int* __restrict__ xmark,
    const float* __restrict__ convw, const float* __restrict__ pmax,
    const float* __restrict__ nyqS, float* __restrict__ out) {
  int tid = threadIdx.x;
  int lane = tid & 63;
  int w = tid >> 6;            // wave 0..7 -> d in [w*64, w*64+64)
  int c = lane & 15;           // A: d-row in tile / B: t-col / C: t-col
  int g = lane >> 4;           // k-slot group 0..3 / C: d-subgroup
  int blk = blockIdx.x;
  int b = blk >> 5;            // 32 t-blocks per batch
  int bt0 = (blk & 31) * (16 * NS);

  // Nyquist-argmax channel count m for batch b (cheap, redundant per thread)
  int m = 0;
#pragma unroll
  for (int nn = 0; nn < 8; ++nn) {
    int bn = b * 8 + nn;
    float mx = fmaxf(pmax[2 * bn], pmax[2 * bn + 1]);
    float S = nyqS[bn];
    if (S * S > mx) ++m;
  }
  float w1 = (float)(8 - m) * 0.125f;  // weight on fixed-emb row t
  float w0 = (float)m * 0.125f;        // weight on row 0 = [0,1,0,1,...]

  // ---- A-frags (const per block): conv weights (g<3) / temporal tab (g==3)
  bf16x8 afrag[DTW];
#pragma unroll
  for (int q = 0; q < DTW; ++q) {
    int dt = w * DTW + q;
    int d = dt * 16 + c;
    if (g < 3) {
      const float* wb = convw + d * 24 + g;   // A[d][g*8+j] = W[d][n=j][k=g]
#pragma unroll
      for (int j = 0; j < 8; ++j) afrag[q][j] = f2bf(wb[j * 3]);
    } else {
      // tab_p[d]: even d -> sin(p*div_{d/2}), odd d -> cos(p*div_{d/2})
      float divv = expf((float)(d >> 1) * NEG_LDIV);
      float s1, c1;
      sincosf(divv, &s1, &c1);
      int odd = d & 1;
      afrag[q][0] = f2bf(odd ? 1.f : 0.f);     // p=0: sin0/cos0
      float ps = s1, pc = c1;
      afrag[q][1] = f2bf(odd ? pc : ps);
#pragma unroll
      for (int p = 2; p < 7; ++p) {
        float ns = fmaf(ps, c1, pc * s1);
        float nc = fmaf(pc, c1, -ps * s1);
        ps = ns; pc = nc;
        afrag[q][p] = f2bf(odd ? pc : ps);
      }
      afrag[q][7] = 0;                          // marks < 7
    }
  }

  // ---- cyc rotating pairs: per (q, h): sin/cos(t_lane * div_i), step 16*div
  // epilogue d = dt*16 + g*4 + r -> i-pairs i0=(dt*16+g*4)/2, i0+1
  float cyS[DTW][2], cyC[DTW][2], rtS[DTW][2], rtC[DTW][2];
  float tl = (float)(bt0 + c);                  // lane's t (C col)
#pragma unroll
  for (int q = 0; q < DTW; ++q) {
#pragma unroll
    for (int h = 0; h < 2; ++h) {
      int i = (((w * DTW + q) * 16 + g * 4) >> 1) + h;
      float divv = expf((float)i * NEG_LDIV);
      sincosf(tl * divv, &cyS[q][h], &cyC[q][h]);
      sincosf(16.f * divv, &rtS[q][h], &rtC[q][h]);
    }
  }

  const f32x4 zac = {0.f, 0.f, 0.f, 0.f};
#pragma unroll
  for (int s = 0; s < NS; ++s) {
    int t0 = bt0 + s * 16;
    // B-frag: x-window rows (g<3) / mark counts (g==3)
    bf16x8 bfrag;
    if (g < 3) {
      int row = (t0 + c + g - 1) & (T_ - 1);    // circular pad
      const float4* xr = (const float4*)(x + ((size_t)b * T_ + row) * N_);
      float4 lo = xr[0], hi = xr[1];
      bfrag[0] = f2bf(lo.x); bfrag[1] = f2bf(lo.y);
      bfrag[2] = f2bf(lo.z); bfrag[3] = f2bf(lo.w);
      bfrag[4] = f2bf(hi.x); bfrag[5] = f2bf(hi.y);
      bfrag[6] = f2bf(hi.z); bfrag[7] = f2bf(hi.w);
    } else {
      int4 mk = *(const int4*)(xmark + ((size_t)b * T_ + t0 + c) * 4);
#pragma unroll
      for (int p = 0; p < 8; ++p) {
        int cv = (mk.x == p) + (mk.y == p) + (mk.z == p) + (mk.w == p);
        bfrag[p] = f2bf((float)cv);
      }
    }
#pragma unroll
    for (int q = 0; q < DTW; ++q) {
      f32x4 acc = __builtin_amdgcn_mfma_f32_16x16x32_bf16(
          afrag[q], bfrag, zac, 0, 0, 0);
      // C row r -> d = dt*16 + g*4 + r; r even: +w1*sin, r odd: +w1*cos+w0
      float4 ov;
      ov.x = fmaf(w1, cyS[q][0], acc[0]);
      ov.y = fmaf(w1, cyC[q][0], acc[1]) + w0;
      ov.z = fmaf(w1, cyS[q][1], acc[2]);
      ov.w = fmaf(w1, cyC[q][1], acc[3]) + w0;
      int dt = w * DTW + q;
      *(float4*)(out + ((size_t)b * T_ + t0 + c) * D_ + dt * 16 + g * 4) = ov;
    }
    // advance cyc pairs by 16 t-steps
#pragma unroll
    for (int q = 0; q < DTW; ++q)
#pragma unroll
      for (int h = 0; h < 2; ++h) {
        float ns = fmaf(cyS[q][h], rtC[q][h], cyC[q][h] * rtS[q][h]);
        float nc = fmaf(cyC[q][h], rtC[q][h], -cyS[q][h] * rtS[q][h]);
        cyS[q][h] = ns; cyC[q][h] = nc;
      }
  }
}

extern "C" void kernel_launch(void* const* d_in, const int* in_sizes, int n_in,
                              void* d_out, int out_size, void* d_ws, size_t ws_size,
                              hipStream_t stream) {
  const float* x = (const float*)d_in[0];
  const int* xmark = (const int*)d_in[1];
  const float* convw = (const float*)d_in[2];
  float* out = (float*)d_out;

  float* pmax = (float*)d_ws;        // 256 floats
  float* nyqS = pmax + 256;          // 128 floats

  fft_kernel<<<256, 1024, 0, stream>>>(x, pmax, nyqS);
  main_kernel<<<B_ * (T_ / (16 * NS)), 512, 0, stream>>>(x, xmark, convw,
                                                         pmax, nyqS, out);
}